// Round 3
// baseline (265.783 us; speedup 1.0000x reference)
//
#include <hip/hip_runtime.h>
#include <cstdint>
#include <cstddef>

#define B_    8
#define N_    2048
#define FIN   128
#define FOUT  64
#define ALPHA 0.2f
#define NEG_BIG -9.0e15f

typedef __attribute__((ext_vector_type(8))) _Float16 half8;
typedef __attribute__((ext_vector_type(4))) float float4v;

// ---------------------------------------------------------------------------
// Kernel 1: wh = x @ W  (fp32 accumulate), store whT[b][f][j] as fp16,
//           s1 = wh@a1, s2 = wh@a2 (fp32).
// wave-per-row: lane = output feature, x row broadcast via scalar loads.
// ---------------------------------------------------------------------------
__global__ __launch_bounds__(256, 4) void k1_wh(
    const float* __restrict__ x, const float* __restrict__ W,
    const float* __restrict__ w2, _Float16* __restrict__ whT,
    float* __restrict__ s1, float* __restrict__ s2)
{
    int t = threadIdx.x, lane = t & 63, w = t >> 6;
    float a1 = w2[lane], a2 = w2[FOUT + lane];
    int rowBase = blockIdx.x * 32 + w * 8;   // 32 rows/block, 8 rows/wave
    for (int rr = 0; rr < 8; ++rr) {
        int row = __builtin_amdgcn_readfirstlane(rowBase + rr);  // wave-uniform
        const float* xr = x + (size_t)row * FIN;
        float acc = 0.f;
        #pragma unroll
        for (int k = 0; k < FIN; ++k)
            acc = fmaf(xr[k], W[k * FOUT + lane], acc);
        int b = row >> 11, j = row & (N_ - 1);
        whT[((size_t)b * FOUT + lane) * N_ + j] = (_Float16)acc;
        float p1 = acc * a1, p2 = acc * a2;
        #pragma unroll
        for (int m = 32; m >= 1; m >>= 1) {
            p1 += __shfl_xor(p1, m);
            p2 += __shfl_xor(p2, m);
        }
        if (lane == 0) { s1[row] = p1; s2[row] = p2; }
    }
}

// ---------------------------------------------------------------------------
// Kernel 2: flash-style masked softmax + PV via MFMA, double-buffered LDS p.
// Block = 16 rows x full j (2048), 4 waves.
//  p-phase : wave w owns rows w*4..w*4+3; adj read fully coalesced
//            (lane*32B contiguous); p (fp16) -> LDS pT[buf][16][520].
//  MFMA    : wave w owns features w*16..w*16+15 over full K; A from LDS,
//            B from L2-resident whT; accumulator stays in registers.
// Pipeline: ONE barrier per 512-chunk — p(c+1) -> buf[1-cur] shares the
// barrier interval with MFMA(c) from buf[cur], so next-chunk adj HBM loads
// overlap current-chunk LDS reads + MFMA (flash-attn-style dbuf).
// m^ = leaky(s1_i + max_j s2_j) >= true row max -> no online rescaling;
// masked entries floor at exp(-76) ~ 0 (also reproduces uniform softmax
// for an all-masked row). A-frag: row=lane&15, k=quad*8+e. C/D: col=lane&15,
// row=quad*4+reg. pT row stride 520 fp16 -> A-reads land 8 lanes per 4-bank
// group = structural minimum, conflict-free.
// ---------------------------------------------------------------------------
__global__ __launch_bounds__(256, 4) void k2_attn(
    const int* __restrict__ adj, const _Float16* __restrict__ whT,
    const float* __restrict__ s1, const float* __restrict__ s2,
    float* __restrict__ out)
{
    __shared__ __attribute__((aligned(16))) _Float16 pT[2][16][520];
    __shared__ float lL[16];
    __shared__ float smaxL[4];

    int t = threadIdx.x, lane = t & 63, w = t >> 6;
    int b = blockIdx.x >> 7;
    int i0 = (blockIdx.x & 127) << 4;

    // --- exact S2MAX over batch b (8 KB, L2-hot) ---
    const float4* s2v = (const float4*)(s2 + (size_t)b * N_);
    float4 ua = s2v[t], ub = s2v[t + 256];
    float vm = fmaxf(fmaxf(fmaxf(ua.x, ua.y), fmaxf(ua.z, ua.w)),
                     fmaxf(fmaxf(ub.x, ub.y), fmaxf(ub.z, ub.w)));
    #pragma unroll
    for (int m = 32; m >= 1; m >>= 1) vm = fmaxf(vm, __shfl_xor(vm, m));
    if (lane == 0) smaxL[w] = vm;
    __syncthreads();
    float s2max = fmaxf(fmaxf(smaxL[0], smaxL[1]), fmaxf(smaxL[2], smaxL[3]));

    int l15 = lane & 15, quad = lane >> 4;
    int f0 = w * 16;

    float s1r[4], negmh[4], lacc[4];
    #pragma unroll
    for (int rr = 0; rr < 4; ++rr) {
        float sv = s1[(size_t)b * N_ + i0 + w * 4 + rr];  // wave-uniform
        float mh = sv + s2max;
        mh = fmaxf(mh, ALPHA * mh);      // leaky(s1_i + s2max) >= row max
        s1r[rr] = sv;
        negmh[rr] = -mh;
        lacc[rr] = 0.f;
    }

    const int*      adjB = adj + ((size_t)b * N_ + i0 + w * 4) * N_ + lane * 8;
    const float*    s2B  = s2 + (size_t)b * N_ + lane * 8;
    const _Float16* wB   = whT + ((size_t)b * FOUT + f0 + l15) * N_ + quad * 8;

    float4v acc = {0, 0, 0, 0};

    auto p_phase = [&](int c, int buf) {
        int jc = c * 512;
        const float* s2c = s2B + jc;
        float4 sa = *(const float4*)s2c;
        float4 sb = *(const float4*)(s2c + 4);
        float ss[8] = {sa.x, sa.y, sa.z, sa.w, sb.x, sb.y, sb.z, sb.w};
        #pragma unroll
        for (int rr = 0; rr < 4; ++rr) {
            const int* ap = adjB + (size_t)rr * N_ + jc;
            int4 aj0 = *(const int4*)ap;
            int4 aj1 = *(const int4*)(ap + 4);
            int aa[8] = {aj0.x, aj0.y, aj0.z, aj0.w, aj1.x, aj1.y, aj1.z, aj1.w};
            half8 pf;
            float ls = 0.f;
            #pragma unroll
            for (int e = 0; e < 8; ++e) {
                float v = s1r[rr] + ss[e];
                v = fmaxf(v, ALPHA * v);                 // leaky relu
                v = (aa[e] > 0) ? v : NEG_BIG;           // mask
                float tt = fmaxf(v + negmh[rr], -76.f);  // masked -> exp ~ 0
                float p = __expf(tt);                    // p in (0,1]
                ls += p;
                pf[e] = (_Float16)p;
            }
            lacc[rr] += ls;
            *(half8*)&pT[buf][w * 4 + rr][lane * 8] = pf;  // contiguous b128
        }
    };

    // prologue: stage chunk 0
    p_phase(0, 0);
    __syncthreads();

    #pragma unroll
    for (int c = 0; c < 4; ++c) {
        if (c < 3) {
            p_phase(c + 1, (c + 1) & 1);   // next chunk -> other buffer
        } else {
            // all p done: reduce row sums before this iteration's barrier
            #pragma unroll
            for (int rr = 0; rr < 4; ++rr) {
                float v = lacc[rr];
                #pragma unroll
                for (int m = 32; m >= 1; m >>= 1) v += __shfl_xor(v, m);
                if (lane == 0) lL[w * 4 + rr] = v;
            }
        }
        // MFMA over chunk c from buf[c&1] (same barrier interval as p(c+1))
        const _Float16* wp = wB + c * 512;
        #pragma unroll
        for (int kk = 0; kk < 16; ++kk) {
            half8 af = *(const half8*)&pT[c & 1][l15][kk * 32 + quad * 8];
            half8 bf = *(const half8*)(wp + kk * 32);
            acc = __builtin_amdgcn_mfma_f32_16x16x32_f16(af, bf, acc, 0, 0, 0);
        }
        __syncthreads();
    }

    // epilogue: normalize, ELU, store. D: row=quad*4+reg, col=f0+l15
    #pragma unroll
    for (int reg = 0; reg < 4; ++reg) {
        int row = quad * 4 + reg;
        float val = acc[reg] / lL[row];
        val = (val > 0.f) ? val : (__expf(val) - 1.f);   // ELU
        out[((size_t)b * N_ + i0 + row) * FOUT + f0 + l15] = val;
    }
}

// ---------------------------------------------------------------------------
extern "C" void kernel_launch(void* const* d_in, const int* in_sizes, int n_in,
                              void* d_out, int out_size, void* d_ws, size_t ws_size,
                              hipStream_t stream) {
    const float* x   = (const float*)d_in[0];
    const int*   adj = (const int*)d_in[1];
    const float* W   = (const float*)d_in[2];
    const float* w2  = (const float*)d_in[3];
    float* out = (float*)d_out;

    _Float16* whT = (_Float16*)d_ws;                                  // 2 MiB
    float* s1 = (float*)((char*)d_ws + (size_t)B_ * FOUT * N_ * 2);   // 64 KiB
    float* s2 = s1 + (size_t)B_ * N_;                                 // 64 KiB

    k1_wh<<<(B_ * N_) / 32, 256, 0, stream>>>(x, W, w2, whT, s1, s2);
    k2_attn<<<(B_ * N_) / 16, 256, 0, stream>>>(adj, whT, s1, s2, out);
}